// Round 23
// baseline (224.292 us; speedup 1.0000x reference)
//
#include <hip/hip_runtime.h>

typedef __attribute__((ext_vector_type(8)))  short bf16x8;   // 8 bf16 = 4 VGPR MFMA operand
typedef __attribute__((ext_vector_type(16))) float f32x16;   // 32x32 MFMA accumulator

#define XIM (32*256*256)

__device__ __forceinline__ short f2bf(float f){
    unsigned int u = __builtin_bit_cast(unsigned int, f);
    u += 0x7fffu + ((u >> 16) & 1u);           // RNE, no NaN inputs here
    return (short)(u >> 16);
}
__device__ __forceinline__ float bf2f(short s){
    unsigned int u = ((unsigned int)(unsigned short)s) << 16;
    return __builtin_bit_cast(float, u);
}
__device__ __forceinline__ void glds16(const short* g, short* l){
    __builtin_amdgcn_global_load_lds(
        (const __attribute__((address_space(1))) unsigned int*)g,
        (__attribute__((address_space(3))) unsigned int*)l,
        16, 0, 0);
}

// ---- prep: folded weights W'_e = W_e + W_s -> wt2[es8][tap9][cio4][cout32][8ci] bf16 (144KB);
//      biasmat[c32][k16] (k<8: eb+sb, else 0) ----
__global__ __launch_bounds__(256) void prep_weights(const float* __restrict__ ew,
                                                    const float* __restrict__ sw,
                                                    const float* __restrict__ ebv,
                                                    const float* __restrict__ sbv,
                                                    short* __restrict__ wt2){
    int i = blockIdx.x * 256 + threadIdx.x;      // 290 blocks * 256 = 74240 exactly
    if(i < 73728){
        int c7  = i & 7;
        int col = (i >> 3) & 31;                 // cout
        int cio = (i >> 8) & 3;                  // ci octet
        int rest = i >> 10;                      // 0..71
        int tap = rest % 9;
        int es  = rest / 9;                      // 0..7
        int ci  = cio*8 + c7;
        float v = ew[((es*32 + col)*32 + ci)*9 + tap] + sw[(col*32 + ci)*9 + tap];
        wt2[i] = f2bf(v);
    } else {                                     // biasmat
        int j = i - 73728, c = j >> 4, k = j & 15;
        float v = (k < 8) ? (ebv[k*32 + c] + sbv[c]) : 0.f;
        wt2[i] = f2bf(v);
    }
}

// ---- gate: 512 blocks x 4 rows, 512 thr (thread = px, row-pair); dbuf 4-ci chunks;
//      3 blocks/CU = 24 waves/CU. fp32 conv -> top2 (fp64 on tight margin) -> route ----
__global__ __launch_bounds__(512) void gate_kernel(const float* __restrict__ x,
                                                   const float* __restrict__ gw,
                                                   const float* __restrict__ gb,
                                                   short* __restrict__ route){
    __shared__ float xs[2][24][272];             // 2 bufs x [r6*4+cid][4+xx], 52.2 KB
    int raw = blockIdx.x;                        // 512; XCD chunk swizzle (512%8==0)
    int wg  = (raw & 7)*64 + (raw >> 3);
    int b   = wg >> 6;
    int y0  = (wg & 63) * 4;
    int t   = threadIdx.x;                       // 0..511
    int wv  = t >> 6, lane = t & 63;
    int px  = t & 255, rh = t >> 8;              // thread: rows {2rh, 2rh+1} at column px
    const float* xim = x + (size_t)b * XIM;

    if(t < 96){                                  // edge zeros, both bufs; persist
        int bufi = t / 48, rem = t % 48, seg = rem >> 1;
        if(rem & 1) xs[bufi][seg][260] = 0.f; else xs[bufi][seg][3] = 0.f;
    }

    auto STAGE = [&](int cc, int bufi){          // 24 segs over 8 waves, float4 per lane
        #pragma unroll
        for(int sg=0; sg<3; ++sg){
            int seg = wv*3 + sg;
            int r6  = seg >> 2, cid = seg & 3;   // staged rows y0-1 .. y0+4
            int ci  = cc*4 + cid;
            int yy  = y0 - 1 + r6;
            const float* xr = xim + ((size_t)ci*256 + yy)*256;
            float4 v = make_float4(0.f,0.f,0.f,0.f);
            if(yy >= 0 && yy < 256) v = *(const float4*)(xr + lane*4);
            *(float4*)(&xs[bufi][seg][4 + lane*4]) = v;
        }
    };

    float g[2][8];
    #pragma unroll
    for(int pr=0;pr<2;++pr)
        #pragma unroll
        for(int e=0;e<8;++e) g[pr][e] = 0.f;

    STAGE(0, 0);
    __syncthreads();                             // chunk0 + edge zeros visible
    for(int cc=0; cc<8; ++cc){                   // ci chunks of 4
        if(cc < 7) STAGE(cc+1, (cc+1)&1);        // prefetch overlaps compute below
        const int bufi = cc & 1;
        #pragma unroll
        for(int cid=0; cid<4; ++cid){
            float sv[4][3];                      // staged rows 2rh .. 2rh+3
            #pragma unroll
            for(int s=0;s<4;++s){
                sv[s][0] = xs[bufi][(rh*2+s)*4+cid][px+3];   // xx = px-1+kw -> idx px+3+kw
                sv[s][1] = xs[bufi][(rh*2+s)*4+cid][px+4];
                sv[s][2] = xs[bufi][(rh*2+s)*4+cid][px+5];
            }
            const float* gwp = gw + (cc*4 + cid)*9;    // gw[e][ci][kh][kw], e-stride 288
            #pragma unroll
            for(int e=0;e<8;++e){
                #pragma unroll
                for(int kh=0;kh<3;++kh){
                    #pragma unroll
                    for(int kw=0;kw<3;++kw){
                        float wval = gwp[e*288 + kh*3 + kw];
                        g[0][e] = fmaf(sv[kh][kw],   wval, g[0][e]);
                        g[1][e] = fmaf(sv[kh+1][kw], wval, g[1][e]);
                    }
                }
            }
        }
        __syncthreads();                         // publish cc+1; reads of buf done before reuse
    }

    #pragma unroll
    for(int pr=0; pr<2; ++pr){
        int y = y0 + rh*2 + pr;
        float v1b=-1e30f, v2b=-1e30f, v3b=-1e30f, r1=0.f, r2=0.f; int i1=-1, i2=-1;
        #pragma unroll
        for(int e=0;e<8;e++){
            float se = 1.f/(1.f + expf(-g[pr][e]));
            float be = se + gb[e];
            if(be > v1b){ v3b=v2b; v2b=v1b; r2=r1; i2=i1; v1b=be; r1=se; i1=e; }
            else if(be > v2b){ v3b=v2b; v2b=be; r2=se; i2=e; }
            else if(be > v3b){ v3b=be; }
        }
        if(v2b - v3b < 2e-5f){                   // fp64 recompute (rare)
            double gd[8];
            #pragma unroll
            for(int e=0;e<8;e++) gd[e] = 0.0;
            for(int ci=0; ci<32; ++ci){
                for(int kh=0; kh<3; ++kh){
                    int yy = y + kh - 1;
                    if(yy < 0 || yy >= 256) continue;
                    const float* xr = xim + ((size_t)ci*256 + yy)*256;
                    for(int kw=0; kw<3; ++kw){
                        int xx = px + kw - 1;
                        if(xx < 0 || xx >= 256) continue;
                        double xv = (double)xr[xx];
                        const float* gwp = gw + ci*9 + kh*3 + kw;
                        #pragma unroll
                        for(int e=0;e<8;e++) gd[e] += xv * (double)gwp[e*288];
                    }
                }
            }
            double b1=-1e30, b2=-1e30; double rr1=0.0, rr2=0.0; int j1=-1, j2=-1;
            #pragma unroll
            for(int e=0;e<8;e++){
                double sd = 1.0/(1.0 + exp(-gd[e]));
                double bd = sd + (double)gb[e];
                if(bd > b1){ b2=b1; rr2=rr1; j2=j1; b1=bd; rr1=sd; j1=e; }
                else if(bd > b2){ b2=bd; rr2=sd; j2=e; }
            }
            i1=j1; i2=j2; r1=(float)rr1; r2=(float)rr2;
        }
        float m  = fmaxf(r1, r2);
        float e1 = expf(r1-m), e2 = expf(r2-m);
        float inv = 1.f/(e1+e2);
        float w1 = e1*inv, w2 = e2*inv;          // ROUTE_SCALE = 1
        bf16x8 ov;
        #pragma unroll
        for(int e=0;e<8;e++){
            float dv = (e==i1) ? w1 : ((e==i2) ? w2 : 0.f);
            ov[e] = f2bf(dv);
        }
        *(bf16x8*)(route + ((size_t)(b*256 + y)*256 + px)*8) = ov;
    }
}

// ---- main (r17/r22-measured): weights-stationary 144KB/block; 2048 blocks x 512 thr;
//      8 waves x 1 row; b128-packed x staging. ----
__global__ __launch_bounds__(512, 2) void moe_main(const float* __restrict__ x,
                                                   const short* __restrict__ wt2,
                                                   const short* __restrict__ route,
                                                   float* __restrict__ out){
    __shared__ __align__(16) short wlds[73728];      // [es8][tap9][cio4][cout32][8ci], 144 KB
    __shared__ __align__(16) short xt[10*2*34*8];    // [row10][cic2][px34][8ci] one hf, 10.88 KB
    int raw = blockIdx.x;                            // 2048; XCD chunk swizzle
    int wg  = (raw & 7)*256 + (raw >> 3);
    int b   = wg >> 8;
    int y0  = ((wg >> 3) & 31) * 8;
    int x0  = (wg & 7) * 32;
    int t   = threadIdx.x;                           // 0..511
    int wv  = t >> 6, l = t & 63, col = l & 31, hi = l >> 5;

    // stage ALL folded weights once: 144 chunks of 1 KB over 8 waves, async
    #pragma unroll
    for(int j=0;j<18;++j){
        int c = wv + 8*j;
        glds16(wt2 + c*512 + l*8, wlds + c*512);
    }

    const float* xim = x + (size_t)b*XIM;
    int yy = y0 + wv;                                // this wave's output row
    bf16x8 biasA = *(const bf16x8*)(wt2 + 73728 + col*16 + hi*8);      // L2-hot
    bf16x8 rfrag = *(const bf16x8*)(route + ((size_t)(b*256 + yy)*256 + x0 + col)*8);

    // x tile: stage per ci-half into xt (b128-packed), cache B-frags in regs
    bf16x8 Bf[3][2][3];                              // [kh][hf][kw] = 72 VGPR
    #pragma unroll
    for(int hf=0; hf<2; ++hf){
        if(hf) __syncthreads();                      // hf0 Bf reads done before overwrite
        // rows y0-1..y0+8, ci = hf*16..+15, px x0-1..x0+32; 8ci packed -> ds_write_b128
        #pragma unroll
        for(int i=0;i<2;++i){
            int u = t + i*512;                       // 640 main units: [row10][cic2][px32]
            if(u < 640){
                int px = u & 31, rc = u >> 5;        // rc 0..19 = row*2+cic
                int row = rc >> 1, cic = rc & 1;
                int cib = hf*16 + cic*8;
                int ry = y0 - 1 + row, xx = x0 - 1 + px;
                bool ok = (ry>=0 && ry<256 && xx>=0 && xx<256);
                bf16x8 pk;
                #pragma unroll
                for(int j2=0;j2<8;++j2){
                    float v = ok ? xim[((size_t)(cib+j2)*256 + ry)*256 + xx] : 0.f;
                    pk[j2] = f2bf(v);
                }
                *(bf16x8*)(&xt[((row*2 + cic)*34 + px)*8]) = pk;
            }
        }
        if(t < 40){                                  // halo units: px 32,33
            int pxh = 32 + (t & 1), rc = t >> 1;     // rc 0..19
            int row = rc >> 1, cic = rc & 1;
            int cib = hf*16 + cic*8;
            int ry = y0 - 1 + row, xx = x0 - 1 + pxh;
            bool ok = (ry>=0 && ry<256 && xx>=0 && xx<256);
            bf16x8 pk;
            #pragma unroll
            for(int j2=0;j2<8;++j2){
                float v = ok ? xim[((size_t)(cib+j2)*256 + ry)*256 + xx] : 0.f;
                pk[j2] = f2bf(v);
            }
            *(bf16x8*)(&xt[((row*2 + cic)*34 + pxh)*8]) = pk;
        }
        __syncthreads();                             // xt(hf) staged; 1st also drains weight glds
        #pragma unroll
        for(int kh=0;kh<3;++kh)                      // wave rows wv..wv+2
            #pragma unroll
            for(int kw=0;kw<3;++kw)
                Bf[kh][hf][kw] = *(const bf16x8*)(&xt[(((wv+kh)*2 + hi)*34 + col + kw)*8]);
    }

    f32x16 z = {};
    f32x16 oa = __builtin_amdgcn_mfma_f32_32x32x16_bf16(biasA, rfrag, z, 0,0,0);

    #pragma unroll
    for(int es=0; es<8; ++es){                       // folded experts (shared absorbed)
        f32x16 acc = {};
        #pragma unroll
        for(int tap=0; tap<9; ++tap){
            const int kh = tap/3, kw = tap - kh*3;
            #pragma unroll
            for(int hf=0; hf<2; ++hf){
                bf16x8 a = *(const bf16x8*)(&wlds[(((es*9 + tap)*4 + hf*2 + hi)*32 + col)*8]);
                acc = __builtin_amdgcn_mfma_f32_32x32x16_bf16(a, Bf[kh][hf][kw], acc, 0,0,0);
            }
        }
        float d = bf2f(rfrag[es]);
        #pragma unroll
        for(int r=0;r<16;r++) oa[r] += d*acc[r];
    }

    float* ob = out + (size_t)b*XIM;
    #pragma unroll
    for(int r=0;r<16;r++){
        int c = hi*4 + (r&3) + 8*(r>>2);             // C/D: col=lane&31, row=(r&3)+8*(r>>2)+4*hi
        ob[((size_t)c*256 + yy)*256 + x0 + col] = oa[r];
    }
}

extern "C" void kernel_launch(void* const* d_in, const int* in_sizes, int n_in,
                              void* d_out, int out_size, void* d_ws, size_t ws_size,
                              hipStream_t stream){
    (void)in_sizes; (void)n_in; (void)out_size; (void)ws_size;
    const float* x   = (const float*)d_in[0];
    const float* gw  = (const float*)d_in[1];
    const float* gb  = (const float*)d_in[2];
    const float* ew  = (const float*)d_in[3];
    const float* ebv = (const float*)d_in[4];
    const float* sw  = (const float*)d_in[5];
    const float* sbv = (const float*)d_in[6];
    float* out = (float*)d_out;

    short* route = (short*)d_ws;                          // 524288 px * 8 bf16 = 8.39 MB
    short* wt2   = route + (size_t)8*256*256*8;           // 74240 bf16 (weights+bias)

    prep_weights<<<dim3(290),  dim3(256), 0, stream>>>(ew, sw, ebv, sbv, wt2);
    gate_kernel <<<dim3(512),  dim3(512), 0, stream>>>(x, gw, gb, route);
    moe_main    <<<dim3(2048), dim3(512), 0, stream>>>(x, wt2, route, out);
}